// Round 13
// baseline (999.371 us; speedup 1.0000x reference)
//
#include <hip/hip_runtime.h>
#include <cstddef>

typedef __attribute__((ext_vector_type(8))) short bh8;
typedef __attribute__((ext_vector_type(4))) float f4;

__device__ __forceinline__ float gelu_f(float x){
  return 0.5f * x * (1.0f + erff(x * 0.7071067811865476f));
}

__device__ __forceinline__ unsigned short f2bf(float f){
  unsigned int u = __float_as_uint(f);
  unsigned int r = (u + 0x7FFFu + ((u >> 16) & 1u)) >> 16;
  return (unsigned short)r;
}

__device__ __forceinline__ float bf2f(unsigned short u){
  return __uint_as_float(((unsigned int)u) << 16);
}

__device__ __forceinline__ f4 mfma16(bh8 a, bh8 b, f4 c){
  return __builtin_amdgcn_mfma_f32_16x16x32_bf16(a, b, c, 0, 0, 0);
}

__device__ __forceinline__ void gll16(const unsigned short* src, unsigned short* dst){
  __builtin_amdgcn_global_load_lds(
      (const __attribute__((address_space(1))) unsigned int*)src,
      (__attribute__((address_space(3))) unsigned int*)dst, 16, 0, 0);
}

// gn coef from 8-slice partials PA[(b*8+g)*8+q], s2 at +512
__device__ __forceinline__ void gn_coef8(const float* pa, const float* sc,
                                         const float* bi, int b, int c,
                                         float& sca, float& sh)
{
  const int g = c >> 6;
  float s1 = 0.f, s2 = 0.f;
  #pragma unroll
  for (int q = 0; q < 8; ++q) {
    s1 += pa[(b * 8 + g) * 8 + q];
    s2 += pa[512 + (b * 8 + g) * 8 + q];
  }
  const float mu = s1 * (1.0f / 65536.0f);
  const float var = s2 * (1.0f / 65536.0f) - mu * mu;
  const float rs = rsqrtf(var + 1e-5f);
  sca = sc[c] * rs;
  sh = bi[c] - mu * sca;
}

// ================= big bf16 MFMA GEMM (AMODE4 prologue now sums 32 PB slices)
#define BG_STAGE(dbuf, kofs, BASE, DST) \
  gll16(BASE + (size_t)sr_ * K + (kofs) + ((ss_ ^ (sr_ & 7)) << 3), &DST[dbuf][tid * 8]);

#define BG_LOADA(kofs) { \
  if (AMODE == 3 || AMODE == 4) { \
    const unsigned short* ap16 = Ab16 + (size_t)sr_ * K + (kofs) + ss_ * 8; \
    const uint4 uv = *(const uint4*)ap16; \
    ra0.x = bf2f((unsigned short)(uv.x & 0xffffu)); ra0.y = bf2f((unsigned short)(uv.x >> 16)); \
    ra0.z = bf2f((unsigned short)(uv.y & 0xffffu)); ra0.w = bf2f((unsigned short)(uv.y >> 16)); \
    ra1.x = bf2f((unsigned short)(uv.z & 0xffffu)); ra1.y = bf2f((unsigned short)(uv.z >> 16)); \
    ra1.z = bf2f((unsigned short)(uv.w & 0xffffu)); ra1.w = bf2f((unsigned short)(uv.w >> 16)); \
  } else { \
    const float* ap_ = Afbase + (size_t)sr_ * K + (kofs) + ss_ * 8; \
    ra0 = *(const float4*)ap_; \
    ra1 = *(const float4*)(ap_ + 4); \
  } \
  if (AMODE == 2 || AMODE == 3) { \
    const int bb_ = (m0 + sr_) >> 10; \
    const int ch_ = (kofs) + ss_ * 8; \
    const float4 c0_ = *(const float4*)(gnc + bb_ * 512 + ch_); \
    const float4 c1_ = *(const float4*)(gnc + bb_ * 512 + ch_ + 4); \
    const float4 h0_ = *(const float4*)(gnc + 4096 + bb_ * 512 + ch_); \
    const float4 h1_ = *(const float4*)(gnc + 4096 + bb_ * 512 + ch_ + 4); \
    ra0.x = fmaf(ra0.x, c0_.x, h0_.x); ra0.y = fmaf(ra0.y, c0_.y, h0_.y); \
    ra0.z = fmaf(ra0.z, c0_.z, h0_.z); ra0.w = fmaf(ra0.w, c0_.w, h0_.w); \
    ra1.x = fmaf(ra1.x, c1_.x, h1_.x); ra1.y = fmaf(ra1.y, c1_.y, h1_.y); \
    ra1.z = fmaf(ra1.z, c1_.z, h1_.z); ra1.w = fmaf(ra1.w, c1_.w, h1_.w); \
  } \
  if (AMODE == 4) { \
    const int ch_ = (kofs) + ss_ * 8; \
    const float4 c0_ = *(const float4*)(gncs + ch_); \
    const float4 c1_ = *(const float4*)(gncs + ch_ + 4); \
    const float4 h0_ = *(const float4*)(gncs + 512 + ch_); \
    const float4 h1_ = *(const float4*)(gncs + 512 + ch_ + 4); \
    ra0.x = fmaf(ra0.x, c0_.x, h0_.x); ra0.y = fmaf(ra0.y, c0_.y, h0_.y); \
    ra0.z = fmaf(ra0.z, c0_.z, h0_.z); ra0.w = fmaf(ra0.w, c0_.w, h0_.w); \
    ra1.x = fmaf(ra1.x, c1_.x, h1_.x); ra1.y = fmaf(ra1.y, c1_.y, h1_.y); \
    ra1.z = fmaf(ra1.z, c1_.z, h1_.z); ra1.w = fmaf(ra1.w, c1_.w, h1_.w); \
  } }

#define BG_WRITEA(dbuf) { \
  const int slot_ = ss_ ^ (sr_ & 7); \
  bh8 av_; \
  av_[0] = (short)f2bf(ra0.x); av_[1] = (short)f2bf(ra0.y); \
  av_[2] = (short)f2bf(ra0.z); av_[3] = (short)f2bf(ra0.w); \
  av_[4] = (short)f2bf(ra1.x); av_[5] = (short)f2bf(ra1.y); \
  av_[6] = (short)f2bf(ra1.z); av_[7] = (short)f2bf(ra1.w); \
  *(bh8*)(&As[dbuf][sr_ * 64 + slot_ * 8]) = av_; }

template<int AMODE, int OMODE>
__global__ __launch_bounds__(1024)
void k_bgemm(const void* __restrict__ Av, const unsigned short* __restrict__ Bt,
             float* __restrict__ C, unsigned short* __restrict__ OB,
             const float* __restrict__ bias, const float* __restrict__ Res,
             const float* __restrict__ gnc, float* __restrict__ gpart,
             int K, int ldc, int nn)
{
  __shared__ __align__(16) unsigned short As[2][8192];
  __shared__ __align__(16) unsigned short Bs[2][8192];
  __shared__ __align__(16) float gncs[1024];
  const int bid = blockIdx.x, nwg = gridDim.x;
  const int wg = (bid & 7) * (nwg >> 3) + (bid >> 3);
  const int mb = wg / nn;
  const int m0 = mb * 128, n0 = (wg - mb * nn) * 128;
  const int tid = threadIdx.x;
  const int w = tid >> 6, lane = tid & 63;
  const int lr = lane & 15, lh = lane >> 4;
  const int wr = w >> 2, wc = w & 3;
  const int sr_ = tid >> 3, ss_ = tid & 7;
  const unsigned short* Abase = (const unsigned short*)Av + (size_t)m0 * K;
  const unsigned short* Ab16 = (const unsigned short*)Av + (size_t)m0 * K;
  const float* Afbase = (const float*)Av + (size_t)m0 * K;
  const unsigned short* Bbase = Bt + (size_t)n0 * K;
  float4 ra0, ra1;
  f4 acc[2][2] = {};

  if (AMODE == 4) {
    if (tid < 512) {
      const int bq = m0 >> 10, g = tid >> 6;
      float s1 = 0.f, s2 = 0.f;
      #pragma unroll
      for (int q = 0; q < 32; ++q) {
        s1 += gnc[(bq * 8 + g) * 32 + q];
        s2 += gnc[2048 + (bq * 8 + g) * 32 + q];
      }
      const float mu = s1 * (1.0f / 65536.0f);
      const float var = s2 * (1.0f / 65536.0f) - mu * mu;
      const float rs = rsqrtf(var + 1e-5f);
      const float sca = Res[tid] * rs;
      gncs[tid] = sca;
      gncs[512 + tid] = gpart[tid] - mu * sca;
    }
    __syncthreads();
  }

  const int nt = K >> 6;
  if (AMODE == 0) { BG_STAGE(0, 0, Abase, As) }
  else            { BG_LOADA(0) BG_WRITEA(0) }
  BG_STAGE(0, 0, Bbase, Bs)
  __syncthreads();

  for (int t = 0; t < nt; ++t) {
    const int d = t & 1;
    const bool more = (t + 1 < nt);
    if (more) {
      const int kn = (t + 1) << 6;
      if (AMODE == 0) { BG_STAGE(d ^ 1, kn, Abase, As) }
      else            { BG_LOADA(kn) }
      BG_STAGE(d ^ 1, kn, Bbase, Bs)
    }
    #pragma unroll
    for (int kk = 0; kk < 2; ++kk) {
      bh8 af[2], bf[2];
      #pragma unroll
      for (int mi = 0; mi < 2; ++mi) {
        const int R = wr * 32 + mi * 16 + lr;
        af[mi] = *(const bh8*)((const char*)As[d] + R * 128 + (((kk * 4 + lh) ^ (R & 7)) * 16));
      }
      #pragma unroll
      for (int ni = 0; ni < 2; ++ni) {
        const int R = wc * 32 + ni * 16 + lr;
        bf[ni] = *(const bh8*)((const char*)Bs[d] + R * 128 + (((kk * 4 + lh) ^ (R & 7)) * 16));
      }
      #pragma unroll
      for (int mi = 0; mi < 2; ++mi)
        #pragma unroll
        for (int ni = 0; ni < 2; ++ni)
          acc[mi][ni] = mfma16(af[mi], bf[ni], acc[mi][ni]);
    }
    if (more && AMODE != 0) { BG_WRITEA(d ^ 1) }
    __syncthreads();
  }

  float cs1[2], cs2[2];
  #pragma unroll
  for (int ni = 0; ni < 2; ++ni) {
    const int col_l = wc * 32 + ni * 16 + lr;
    const int col = n0 + col_l;
    float bv = 0.f;
    if (OMODE == 1 || OMODE == 2 || OMODE == 4) bv = bias[col];
    if (OMODE == 3) bv = bias[col & 31];
    float s1 = 0.f, s2 = 0.f;
    #pragma unroll
    for (int mi = 0; mi < 2; ++mi) {
      #pragma unroll
      for (int r = 0; r < 4; ++r) {
        const int row = m0 + wr * 32 + mi * 16 + lh * 4 + r;
        float v = acc[mi][ni][r] + bv;
        if (OMODE == 0) {
          C[(size_t)row * ldc + col] = v;
          s1 += v; s2 += v * v;
        } else if (OMODE == 1) {
          OB[(size_t)row * ldc + col] = f2bf(gelu_f(v));
        } else if (OMODE == 2 || OMODE == 4) {
          const size_t ci = (size_t)row * ldc + col;
          v += Res[ci];
          C[ci] = v;
          s1 += v; s2 += v * v;
        } else {
          v = gelu_f(v);
          const int bb = row >> 10, hw = row & 1023, ii = hw >> 5, jj = hw & 31;
          const int dxy = col >> 5, dy = dxy >> 3, dx = dxy & 7, cc = col & 31;
          OB[(((size_t)(bb * 256 + ii * 8 + dy)) * 256 + jj * 8 + dx) * 32 + cc] = f2bf(v);
        }
      }
    }
    cs1[ni] = s1; cs2[ni] = s2;
  }
  if (OMODE == 0 || OMODE == 2 || OMODE == 4) {
    float* sp = (float*)As;
    const int sub = wr * 4 + lh;
    #pragma unroll
    for (int ni = 0; ni < 2; ++ni) {
      const int col_l = wc * 32 + ni * 16 + lr;
      sp[col_l * 16 + sub] = cs1[ni];
      sp[2048 + col_l * 16 + sub] = cs2[ni];
    }
    __syncthreads();
    if (tid < 128) {
      float s1 = 0.f, s2 = 0.f;
      #pragma unroll
      for (int u = 0; u < 16; ++u) { s1 += sp[tid * 16 + u]; s2 += sp[2048 + tid * 16 + u]; }
      const int b = m0 >> 10, slice = (m0 >> 7) & 7;
      if (OMODE == 4) {
        gpart[(b * 8 + slice) * 512 + n0 + tid] = s1;
      } else {
        #pragma unroll
        for (int sft = 32; sft > 0; sft >>= 1) {
          s1 += __shfl_xor(s1, sft, 64);
          s2 += __shfl_xor(s2, sft, 64);
        }
        if ((tid & 63) == 0) {
          const int g = (n0 >> 6) + (tid >> 6);
          gpart[(b * 8 + g) * 8 + slice] = s1;
          gpart[512 + (b * 8 + g) * 8 + slice] = s2;
        }
      }
    }
  }
}

// ================= fused mode pipeline: dft_b + AFNO MLP + idft_d (radix-2 DFTs)
__global__ __launch_bounds__(256)
void k_modes(unsigned int* __restrict__ AB, const unsigned short* __restrict__ Sb_d,
             const float* __restrict__ SB_d)
{
  __shared__ __align__(16) unsigned int ABs[4096];
  __shared__ __align__(16) unsigned short Ws[16384];
  __shared__ __align__(16) unsigned short Ps[4096];
  __shared__ __align__(16) unsigned short O1s[4096];
  __shared__ float ct[512], st[512];
  unsigned short* M2 = (unsigned short*)ABs;

  const int bx = blockIdx.x;
  const int cq = bx & 3, kh = (bx >> 2) & 15, b = bx >> 6;
  const int tid = threadIdx.x;
  const int w = tid >> 6, lane = tid & 63, lr = lane & 15, lh = lane >> 4;
  unsigned int* ABbase = AB + (((size_t)b * 16 + kh) * 32) * 512 + cq * 128;

  #pragma unroll
  for (int p = 0; p < 4; ++p) {
    const int q = p * 256 + tid;
    const int x = q >> 5, c4 = (q & 31) * 4;
    gll16((const unsigned short*)(ABbase + (size_t)x * 512 + c4),
          (unsigned short*)&ABs[q * 4]);
  }
  {
    const unsigned short* Wsrc = Sb_d + (size_t)(cq * 2) * 16384;
    #pragma unroll
    for (int p = 0; p < 8; ++p) {
      const int q = p * 256 + tid;
      const int r = q >> 4, c = q & 15;
      gll16(Wsrc + r * 128 + ((c ^ (r & 7)) << 3), &Ws[q * 8]);
    }
  }
  for (int q = tid; q < 512; q += 256) {
    const int k = q >> 5, xx = q & 31;
    const float ang = (float)((k * xx) & 31) * 0.19634954084936207f;
    ct[q] = cosf(ang); st[q] = sinf(ang);
  }
  __syncthreads();

  // ---- dft_b (radix-2)
  const int cc = tid & 127, kp2 = tid >> 7;
  {
    float gr[8], gi[8];
    #pragma unroll
    for (int j = 0; j < 8; ++j) { gr[j] = 0.f; gi[j] = 0.f; }
    for (int x = 0; x < 16; ++x) {
      const unsigned int p1 = ABs[x * 128 + cc];
      const unsigned int p2 = ABs[(x + 16) * 128 + cc];
      const float vr1 = bf2f((unsigned short)(p1 & 0xffffu));
      const float vi1 = bf2f((unsigned short)(p1 >> 16));
      const float vr2 = bf2f((unsigned short)(p2 & 0xffffu));
      const float vi2 = bf2f((unsigned short)(p2 >> 16));
      const float vr = kp2 ? (vr1 - vr2) : (vr1 + vr2);
      const float vi = kp2 ? (vi1 - vi2) : (vi1 + vi2);
      #pragma unroll
      for (int j = 0; j < 8; ++j) {
        const int kg = 2 * j + kp2;
        const float c_ = ct[kg * 32 + x], s_ = st[kg * 32 + x];
        gr[j] += vr * c_ + vi * s_;
        gi[j] += vi * c_ - vr * s_;
      }
    }
    const int cblk = cc >> 6, ci = cc & 63;
    #pragma unroll
    for (int j = 0; j < 8; ++j) {
      const int kw = 2 * j + kp2;
      const int base = cblk * 2048 + kw * 128;
      const int chr = (ci >> 3) ^ (kw & 7);
      const int chi = ((64 + ci) >> 3) ^ (kw & 7);
      Ps[base + (chr << 3) + (ci & 7)] = f2bf(gr[j] * (1.0f / 32.0f));
      Ps[base + (chi << 3) + (ci & 7)] = f2bf(gi[j] * (1.0f / 32.0f));
    }
  }
  __syncthreads();

  // ---- AFNO: 4 iters, W single-buffer
  for (int i = 0; i < 4; ++i) {
    const int cblk = i & 1;
    const unsigned short* src = (i < 2) ? Ps : O1s;
    f4 acc[2] = {};
    #pragma unroll
    for (int ks = 0; ks < 4; ++ks) {
      const bh8 a = *(const bh8*)(&src[cblk * 2048 + lr * 128
                      + (((ks * 4 + lh) ^ (lr & 7)) << 3)]);
      #pragma unroll
      for (int j = 0; j < 2; ++j) {
        const int rw = (w * 2 + j) * 16 + lr;
        const bh8 bb = *(const bh8*)(&Ws[rw * 128 + (((ks * 4 + lh) ^ (rw & 7)) << 3)]);
        acc[j] = mfma16(a, bb, acc[j]);
      }
    }
    const int z = cq * 2 + cblk;
    #pragma unroll
    for (int j = 0; j < 2; ++j) {
      const int o = (w * 2 + j) * 16 + lr;
      if (i < 2) {
        const float bv = SB_d[z * 128 + o];
        #pragma unroll
        for (int r = 0; r < 4; ++r) {
          const int kw = lh * 4 + r;
          const int ch = (o >> 3) ^ (kw & 7);
          O1s[cblk * 2048 + kw * 128 + (ch << 3) + (o & 7)] = f2bf(gelu_f(acc[j][r] + bv));
        }
      } else {
        const float bv = SB_d[1024 + z * 128 + o];
        #pragma unroll
        for (int r = 0; r < 4; ++r) {
          const int kw = lh * 4 + r;
          M2[cblk * 2048 + kw * 128 + o] = f2bf(acc[j][r] + bv);
        }
      }
    }
    __syncthreads();
    if (i < 3) {
      const int j2 = i + 1;
      const unsigned short* Wsrc = Sb_d + (j2 >= 2 ? 131072 : 0)
                                 + (size_t)(cq * 2 + (j2 & 1)) * 16384;
      #pragma unroll
      for (int p = 0; p < 8; ++p) {
        const int q = p * 256 + tid;
        const int r = q >> 4, c = q & 15;
        gll16(Wsrc + r * 128 + ((c ^ (r & 7)) << 3), &Ws[q * 8]);
      }
      __syncthreads();
    }
  }

  // ---- idft_d (radix-2): pair outputs (x, x+16)
  {
    const int xh = tid >> 7;
    const int cblk = cc >> 6, ci = cc & 63;
    float gr[16], gi[16];
    #pragma unroll
    for (int kw = 0; kw < 16; ++kw) {
      const float wf = (kw == 0) ? 1.0f : 2.0f;
      gr[kw] = wf * bf2f(M2[cblk * 2048 + kw * 128 + ci]);
      gi[kw] = wf * bf2f(M2[cblk * 2048 + kw * 128 + 64 + ci]);
    }
    for (int x = xh * 8; x < xh * 8 + 8; ++x) {
      float Er = 0.f, Ei = 0.f, Or = 0.f, Oi = 0.f;
      #pragma unroll
      for (int j = 0; j < 8; ++j) {
        const int ke = 2 * j, ko = 2 * j + 1;
        const float ce = ct[ke * 32 + x], se = st[ke * 32 + x];
        const float co = ct[ko * 32 + x], so = st[ko * 32 + x];
        Er += gr[ke] * ce - gi[ke] * se;
        Ei += gi[ke] * ce + gr[ke] * se;
        Or += gr[ko] * co - gi[ko] * so;
        Oi += gi[ko] * co + gr[ko] * so;
      }
      ABbase[(size_t)x * 512 + cc] =
          (unsigned int)f2bf(Er + Or) | ((unsigned int)f2bf(Ei + Oi) << 16);
      ABbase[(size_t)(x + 16) * 512 + cc] =
          (unsigned int)f2bf(Er - Or) | ((unsigned int)f2bf(Ei - Oi) << 16);
    }
  }
}

// ---------------- im2col pack: x -> bf16 imat [32768][448]
__global__ __launch_bounds__(256)
void k_pack(const float* __restrict__ x, unsigned short* __restrict__ imat)
{
  const int nb = blockIdx.x;
  const int j = nb & 31, i = (nb >> 5) & 31, b = nb >> 10;
  const int tid = threadIdx.x;
  const int tl = tid >> 6, px = tid & 63;
  const int dy = px >> 3, dx = px & 7;
  const int Y = i * 8 + dy, X = j * 8 + dx;
  const float4 v = *(const float4*)(x + (((size_t)(b * 256 + Y)) * 256 + X) * 16 + tl * 4);
  const size_t row = (size_t)nb * 4 + tl;
  ushort4 ov;
  ov.x = f2bf(v.x); ov.y = f2bf(v.y); ov.z = f2bf(v.z); ov.w = f2bf(v.w);
  *(ushort4*)(imat + row * 448 + px * 4) = ov;
  for (int q = tid; q < 768; q += 256) {
    const int tt = q / 192, r = q - tt * 192;
    const int sec = r >> 6, p2 = r & 63;
    float val;
    if (sec == 0)      val = (float)(i * 8 + (p2 >> 3)) * (1.0f / 255.0f);
    else if (sec == 1) val = (float)(j * 8 + (p2 & 7)) * (1.0f / 255.0f);
    else               val = (float)tt * (1.0f / 3.0f);
    imat[((size_t)nb * 4 + tt) * 448 + 256 + sec * 64 + p2] = f2bf(val);
  }
}

// ---------------- prep Bt_patch [64][448] (+ padded bias)
__global__ __launch_bounds__(256)
void k_prep_btp(const float* __restrict__ pw, const float* __restrict__ pb,
                unsigned short* __restrict__ btp, float* __restrict__ pbp)
{
  const int idx = blockIdx.x * 256 + threadIdx.x;
  if (idx < 28672) {
    const int n = idx / 448, k = idx - (idx / 448) * 448;
    int l;
    if (k < 256) { const int pxx = k >> 2, c = k & 3; l = pxx * 7 + c; }
    else { const int sec = (k - 256) >> 6, p2 = (k - 256) & 63; l = p2 * 7 + 4 + sec; }
    btp[n * 448 + k] = (n < 35) ? f2bf(pw[l * 35 + n]) : (unsigned short)0;
  }
  if (idx < 64) pbp[idx] = (idx < 35) ? pb[idx] : 0.0f;
}

// ---------------- prep Bt_embed [512][64]
__global__ __launch_bounds__(256)
void k_prep_bte(const float* __restrict__ w, unsigned short* __restrict__ bte)
{
  const int idx = blockIdx.x * 256 + threadIdx.x;
  const int n = idx >> 6, k = idx & 63;
  bte[idx] = (k < 35) ? f2bf(w[k * 512 + n]) : (unsigned short)0;
}

// ---------------- temb table [4][512]
__global__ __launch_bounds__(256)
void k_temb(const float* __restrict__ gamma, float* __restrict__ temb)
{
  const int idx = blockIdx.x * 256 + threadIdx.x;
  const int t = idx >> 9, e = idx & 511;
  temb[idx] = cosf((float)t * (1.0f / 3.0f) * gamma[e]);
}

// ---------------- weight prep: fp32 [K][N] -> bf16 [N][K]
__global__ __launch_bounds__(256)
void k_cvt_trans(const float* __restrict__ in, unsigned short* __restrict__ out,
                 int K, int N, long long sIn, long long sOut)
{
  __shared__ float tile[32][33];
  const int z = blockIdx.z;
  in  += (size_t)z * sIn;
  out += (size_t)z * sOut;
  const int n0 = blockIdx.x * 32, k0 = blockIdx.y * 32;
  const int tx = threadIdx.x & 31, ty = threadIdx.x >> 5;
  #pragma unroll
  for (int i = 0; i < 4; ++i)
    tile[ty + i * 8][tx] = in[(size_t)(k0 + ty + i * 8) * N + n0 + tx];
  __syncthreads();
  #pragma unroll
  for (int i = 0; i < 4; ++i)
    out[(size_t)(n0 + ty + i * 8) * K + k0 + tx] = f2bf(tile[tx][ty + i * 8]);
}

__global__ __launch_bounds__(256)
void k_cvt(const float* __restrict__ in, unsigned short* __restrict__ out, int n)
{
  const int idx = blockIdx.x * 256 + threadIdx.x;
  if (idx < n) out[idx] = f2bf(in[idx]);
}

__global__ __launch_bounds__(256)
void k_prep_w3(const float* __restrict__ w, unsigned short* __restrict__ out)
{
  const int idx = blockIdx.x * 256 + threadIdx.x;
  if (idx < 9216) {
    const int kb = idx >> 10, co = (idx >> 5) & 31, ci = idx & 31;
    out[idx] = f2bf(w[(kb * 32 + ci) * 32 + co]);
  }
}

// ---------------- small bf16 MFMA GEMM, 64x64 tile, z-batched (patch/embed)
template<int BIAS, int GELU, int OMODE>
__global__ __launch_bounds__(256)
void k_mgemm(const unsigned short* __restrict__ A, const unsigned short* __restrict__ Bt,
             const float* __restrict__ bias, unsigned short* __restrict__ OB,
             const float* __restrict__ pos, const float* __restrict__ temb,
             int K, int lda, int ldc,
             long long zsA, long long zsB, long long zsC, int zsBias)
{
  __shared__ __align__(16) unsigned short As[64 * 40];
  __shared__ __align__(16) unsigned short Bs[64 * 40];
  const int z = blockIdx.z;
  A  += (size_t)z * zsA;
  Bt += (size_t)z * zsB;
  if (BIAS) bias += (size_t)z * zsBias;
  OB += (size_t)z * zsC;
  const int m0 = blockIdx.y * 64, n0 = blockIdx.x * 64;
  const int tid = threadIdx.x;
  const int w = tid >> 6, l = tid & 63;
  const int lr = l & 15, lh = l >> 4;
  const int sr = tid >> 2, skq = (tid & 3) * 8;
  f4 acc[4] = {};
  for (int k0 = 0; k0 < K; k0 += 32) {
    const uint4 av = *(const uint4*)(A + (size_t)(m0 + sr) * lda + k0 + skq);
    *(uint4*)(&As[sr * 40 + skq]) = av;
    const uint4 bv = *(const uint4*)(Bt + (size_t)(n0 + sr) * K + k0 + skq);
    *(uint4*)(&Bs[sr * 40 + skq]) = bv;
    __syncthreads();
    const bh8 af = *(const bh8*)(&As[(w * 16 + lr) * 40 + lh * 8]);
    #pragma unroll
    for (int ct = 0; ct < 4; ++ct) {
      const bh8 bf = *(const bh8*)(&Bs[(ct * 16 + lr) * 40 + lh * 8]);
      acc[ct] = mfma16(af, bf, acc[ct]);
    }
    __syncthreads();
  }
  #pragma unroll
  for (int ct = 0; ct < 4; ++ct) {
    const int col = n0 + ct * 16 + lr;
    float bv = 0.f;
    if (BIAS) bv = bias[col];
    #pragma unroll
    for (int r = 0; r < 4; ++r) {
      const int row = m0 + w * 16 + lh * 4 + r;
      float v = acc[ct][r] + bv;
      if (GELU) v = gelu_f(v);
      if (OMODE == 2) {
        const int hw = (row >> 2) & 1023, t = row & 3;
        v = (v + pos[(size_t)hw * 512 + col]) * temb[t * 512 + col];
        OB[(size_t)row * 512 + col] = f2bf(v);
      } else {
        OB[(size_t)row * ldc + col] = f2bf(v);
      }
    }
  }
}

// ---------------- decoder tail: conv3x3 (MFMA) + gelu + 1x1 -> out
__global__ __launch_bounds__(256)
void k_tail(const unsigned short* __restrict__ Y1, const unsigned short* __restrict__ w3t,
            const float* __restrict__ c1w, const float* __restrict__ c1b,
            float* __restrict__ outp)
{
  __shared__ __align__(16) char lbuf[256 * 33 * 4];
  __shared__ float c1s[128];
  unsigned short* it = (unsigned short*)lbuf;
  float* y2 = (float*)lbuf;
  const int bx = blockIdx.x;
  const int b = bx >> 8, ty = (bx >> 4) & 15, tx = bx & 15;
  const int Y0 = ty * 16, X0 = tx * 16;
  const int tid = threadIdx.x;
  const int w = tid >> 6, l = tid & 63, lr = l & 15, lh = l >> 4;

  if (tid < 128) c1s[tid] = c1w[tid];
  for (int idx = tid; idx < 1296; idx += 256) {
    const int r = idx / 72, rem = idx - r * 72, c = rem >> 2, q = rem & 3;
    const int Yg = Y0 + r - 1, Xg = X0 + c - 1;
    uint4 v = make_uint4(0u, 0u, 0u, 0u);
    if (Yg >= 0 && Yg < 256 && Xg >= 0 && Xg < 256)
      v = *(const uint4*)(Y1 + (((size_t)(b * 256 + Yg)) * 256 + Xg) * 32 + q * 8);
    *(uint4*)(&it[(r * 18 + c) * 40 + q * 8]) = v;
  }
  bh8 bw[2][9];
  #pragma unroll
  for (int ct = 0; ct < 2; ++ct)
    #pragma unroll
    for (int kb = 0; kb < 9; ++kb)
      bw[ct][kb] = *(const bh8*)(w3t + (size_t)(kb * 32 + ct * 16 + lr) * 32 + lh * 8);
  __syncthreads();

  f4 acc[4][2] = {};
  #pragma unroll
  for (int kb = 0; kb < 9; ++kb) {
    const int dy = kb / 3, dx = kb % 3;
    #pragma unroll
    for (int yy = 0; yy < 4; ++yy) {
      const int y = w * 4 + yy;
      const bh8 af = *(const bh8*)(&it[((y + dy) * 18 + lr + dx) * 40 + lh * 8]);
      acc[yy][0] = mfma16(af, bw[0][kb], acc[yy][0]);
      acc[yy][1] = mfma16(af, bw[1][kb], acc[yy][1]);
    }
  }
  __syncthreads();
  #pragma unroll
  for (int yy = 0; yy < 4; ++yy) {
    const int y = w * 4 + yy;
    #pragma unroll
    for (int ct = 0; ct < 2; ++ct)
      #pragma unroll
      for (int r = 0; r < 4; ++r)
        y2[(y * 16 + lh * 4 + r) * 33 + ct * 16 + lr] = gelu_f(acc[yy][ct][r]);
  }
  __syncthreads();
  const int py = tid >> 4, px = tid & 15;
  float o0 = c1b[0], o1 = c1b[1], o2 = c1b[2], o3 = c1b[3];
  #pragma unroll 8
  for (int ci = 0; ci < 32; ++ci) {
    const float v = y2[tid * 33 + ci];
    o0 = fmaf(v, c1s[ci * 4 + 0], o0);
    o1 = fmaf(v, c1s[ci * 4 + 1], o1);
    o2 = fmaf(v, c1s[ci * 4 + 2], o2);
    o3 = fmaf(v, c1s[ci * 4 + 3], o3);
  }
  float4 ov; ov.x = o0; ov.y = o1; ov.z = o2; ov.w = o3;
  *(float4*)(outp + (((size_t)(b * 256 + Y0 + py)) * 256 + X0 + px) * 4) = ov;
}

// ---------------- forward DFT stage A (radix-2, BOTH parities; H read once)
__global__ __launch_bounds__(256)
void k_dft_a(const float* __restrict__ H, const float* __restrict__ PA,
             const float* __restrict__ sc, const float* __restrict__ bi,
             unsigned int* __restrict__ AB)
{
  __shared__ float ct[512], st[512];
  const int tid = threadIdx.x;
  for (int q = tid; q < 512; q += 256) {
    const int k = q >> 5, y = q & 31;
    const float ang = (float)((k * y) & 31) * 0.19634954084936207f;
    ct[q] = cosf(ang); st[q] = sinf(ang);
  }
  __syncthreads();
  const int blk = blockIdx.x;                    // b*64 + x*2 + half
  const int half = blk & 1, x = (blk >> 1) & 31, b = blk >> 6;
  const int c = half * 256 + tid;
  float sca, sh;
  gn_coef8(PA, sc, bi, b, c, sca, sh);
  float ar[16], ai[16];
  #pragma unroll
  for (int k = 0; k < 16; ++k) { ar[k] = 0.f; ai[k] = 0.f; }
  const float* zp = H + ((size_t)b * 1024 + x) * 512 + c;
  for (int y = 0; y < 16; ++y) {
    const float u  = fmaf(zp[(size_t)y * 16384], sca, sh);
    const float w2 = fmaf(zp[(size_t)(y + 16) * 16384], sca, sh);
    const float e = u + w2, o = u - w2;
    #pragma unroll
    for (int j = 0; j < 8; ++j) {
      const int ke = 2 * j, ko = 2 * j + 1;
      ar[ke] = fmaf(e, ct[ke * 32 + y], ar[ke]);
      ai[ke] = fmaf(-e, st[ke * 32 + y], ai[ke]);
      ar[ko] = fmaf(o, ct[ko * 32 + y], ar[ko]);
      ai[ko] = fmaf(-o, st[ko * 32 + y], ai[ko]);
    }
  }
  #pragma unroll
  for (int k = 0; k < 16; ++k) {
    const size_t o = (((size_t)b * 16 + k) * 32 + x) * 512 + c;
    AB[o] = (unsigned int)f2bf(ar[k]) | ((unsigned int)f2bf(ai[k]) << 16);
  }
}

// ---------------- merged AFNO weights for ALL layers
__global__ __launch_bounds__(256)
void k_mode_prep_all(const float* __restrict__ aw1, const float* __restrict__ aw2,
                     const float* __restrict__ ab1, const float* __restrict__ ab2,
                     unsigned short* __restrict__ Sb, float* __restrict__ SB)
{
  const int gi = blockIdx.x * 256 + threadIdx.x;
  const int dd = gi >> 18;
  const int idx = gi & 262143;
  const float* aw1_d = aw1 + (size_t)dd * 65536;
  const float* aw2_d = aw2 + (size_t)dd * 65536;
  const int s = idx >> 17;
  const int blk = (idx >> 14) & 7;
  const int n = (idx >> 7) & 127;
  const int kk = idx & 127;
  const float* aw = s ? aw2_d : aw1_d;
  const int i = kk & 63, o = n & 63;
  const float wr = aw[(blk * 64 + i) * 64 + o];
  const float wi = aw[32768 + (blk * 64 + i) * 64 + o];
  float val;
  if (n < 64) val = (kk < 64) ? wr : -wi;
  else        val = (kk < 64) ? wi :  wr;
  Sb[gi] = f2bf(val);
  if (idx < 2048) {
    const int s2 = idx >> 10, r2 = idx & 1023, b2 = r2 >> 7, q2 = r2 & 127;
    const float* ab = s2 ? (ab2 + dd * 1024) : (ab1 + dd * 1024);
    SB[dd * 2048 + idx] = (q2 < 64) ? ab[b2 * 64 + q2] : ab[512 + b2 * 64 + (q2 - 64)];
  }
}

// ---------------- inverse DFT stage E (radix-2, ALL 32 y; Tp read once) + gn2 partials
__global__ __launch_bounds__(256)
void k_idft_e(const unsigned int* __restrict__ Tp, const float* __restrict__ H,
              const float* __restrict__ PA, const float* __restrict__ sc,
              const float* __restrict__ bi, unsigned short* __restrict__ zab,
              float* __restrict__ PB)
{
  __shared__ float ct[512], st[512];
  const int tid = threadIdx.x;
  for (int q = tid; q < 512; q += 256) {
    const int k = q >> 5, y = q & 31;
    const float ang = (float)((k * y) & 31) * 0.19634954084936207f;
    ct[q] = cosf(ang); st[q] = sinf(ang);
  }
  __syncthreads();
  const int blk = blockIdx.x;                 // b*64 + x*2 + half
  const int half = blk & 1, x = (blk >> 1) & 31, b = blk >> 6;
  const int c = half * 256 + tid;
  float sca, sh;
  gn_coef8(PA, sc, bi, b, c, sca, sh);
  float trv[16], tiv[16];
  #pragma unroll
  for (int k = 0; k < 16; ++k) {
    const size_t o = (((size_t)b * 16 + k) * 32 + x) * 512 + c;
    const unsigned int pv = Tp[o];
    trv[k] = bf2f((unsigned short)(pv & 0xffffu));
    tiv[k] = bf2f((unsigned short)(pv >> 16));
  }
  float s1 = 0.f, s2 = 0.f;
  for (int y = 0; y < 16; ++y) {
    float Ev = 0.f, Ov = 0.f;
    #pragma unroll
    for (int j = 0; j < 8; ++j) {
      const int ke = 2 * j, ko = 2 * j + 1;
      Ev += trv[ke] * ct[ke * 32 + y] - tiv[ke] * st[ke * 32 + y];
      Ov += trv[ko] * ct[ko * 32 + y] - tiv[ko] * st[ko * 32 + y];
    }
    const size_t o1 = ((size_t)b * 1024 + y * 32 + x) * 512 + c;
    const size_t o2 = ((size_t)b * 1024 + (y + 16) * 32 + x) * 512 + c;
    const float zv1 = (Ev + Ov) * (1.0f / 32.0f) + fmaf(H[o1], sca, sh);
    const float zv2 = (Ev - Ov) * (1.0f / 32.0f) + fmaf(H[o2], sca, sh);
    zab[o1] = f2bf(zv1);
    zab[o2] = f2bf(zv2);
    s1 += zv1 + zv2; s2 += zv1 * zv1 + zv2 * zv2;
  }
  #pragma unroll
  for (int sft = 32; sft > 0; sft >>= 1) {
    s1 += __shfl_xor(s1, sft, 64);
    s2 += __shfl_xor(s2, sft, 64);
  }
  if ((tid & 63) == 0) {
    const int g = half * 4 + (tid >> 6);
    PB[(b * 8 + g) * 32 + x] = s1;
    PB[2048 + (b * 8 + g) * 32 + x] = s2;
  }
}

// ---------------- cls layers 1/2 (ILP-4 accumulators)
template<int FIRST>
__global__ __launch_bounds__(256)
void k_cls_l(const float* __restrict__ src, const float* __restrict__ Wm,
             const float* __restrict__ bb, float* __restrict__ Cout)
{
  __shared__ float tok[512];
  __shared__ float red[256];
  const int b = blockIdx.y, oc = blockIdx.x;
  const int tid = threadIdx.x;
  for (int i = tid; i < 512; i += 256) {
    if (FIRST) {
      float s = 0.f;
      #pragma unroll
      for (int q = 0; q < 8; ++q) s += src[((b * 8 + q) << 9) + i];
      tok[i] = s * (1.0f / 1024.0f);
    } else {
      tok[i] = src[b * 512 + i];
    }
  }
  __syncthreads();
  const int to = tid & 63, iq = tid >> 6;
  const int o = oc * 64 + to;
  const float* wp = Wm + (size_t)(iq * 128) * 512 + o;
  const float* tp = tok + iq * 128;
  float a0 = 0.f, a1 = 0.f, a2 = 0.f, a3 = 0.f;
  #pragma unroll 8
  for (int i = 0; i < 128; i += 4) {
    a0 = fmaf(tp[i + 0], wp[(size_t)(i + 0) * 512], a0);
    a1 = fmaf(tp[i + 1], wp[(size_t)(i + 1) * 512], a1);
    a2 = fmaf(tp[i + 2], wp[(size_t)(i + 2) * 512], a2);
    a3 = fmaf(tp[i + 3], wp[(size_t)(i + 3) * 512], a3);
  }
  red[tid] = (a0 + a1) + (a2 + a3);
  __syncthreads();
  if (tid < 64) {
    const int oo = oc * 64 + tid;
    const float v = red[tid] + red[tid + 64] + red[tid + 128] + red[tid + 192] + bb[oo];
    Cout[b * 512 + oo] = gelu_f(v);
  }
}

// ---------------- cls layer 3
__global__ __launch_bounds__(768)
void k_cls3(const float* __restrict__ C2, const float* __restrict__ w3,
            const float* __restrict__ b3, float* __restrict__ outp)
{
  const int b = blockIdx.x, tid = threadIdx.x;
  const int o = tid >> 6, lane = tid & 63;
  float acc = 0.f;
  for (int i = lane; i < 512; i += 64)
    acc = fmaf(C2[b * 512 + i], w3[i * 12 + o], acc);
  #pragma unroll
  for (int s = 32; s > 0; s >>= 1) acc += __shfl_xor(acc, s, 64);
  if (lane == 0) outp[2097152 + b * 12 + o] = acc + b3[o];
}

extern "C" void kernel_launch(void* const* d_in, const int* in_sizes, int n_in,
                              void* d_out, int out_size, void* d_ws, size_t ws_size,
                              hipStream_t stream)
{
  (void)in_sizes; (void)n_in; (void)out_size; (void)ws_size;
  const float* x      = (const float*)d_in[0];
  const float* patch_w= (const float*)d_in[1];
  const float* patch_b= (const float*)d_in[2];
  const float* p1_w   = (const float*)d_in[3];
  const float* p1_b   = (const float*)d_in[4];
  const float* pos    = (const float*)d_in[5];
  const float* tagg_w = (const float*)d_in[6];
  const float* gamma  = (const float*)d_in[7];
  const float* gn1_s  = (const float*)d_in[8];
  const float* gn1_b  = (const float*)d_in[9];
  const float* aw1    = (const float*)d_in[10];
  const float* ab1    = (const float*)d_in[11];
  const float* aw2    = (const float*)d_in[12];
  const float* ab2    = (const float*)d_in[13];
  const float* gn2_s  = (const float*)d_in[14];
  const float* gn2_b  = (const float*)d_in[15];
  const float* mw1    = (const float*)d_in[16];
  const float* mb1    = (const float*)d_in[17];
  const float* mw2    = (const float*)d_in[18];
  const float* mb2    = (const float*)d_in[19];
  const float* cls_w1 = (const float*)d_in[20];
  const float* cls_b1 = (const float*)d_in[21];
  const float* cls_w2 = (const float*)d_in[22];
  const float* cls_b2 = (const float*)d_in[23];
  const float* cls_w3 = (const float*)d_in[24];
  const float* cls_b3 = (const float*)d_in[25];
  const float* dec_w  = (const float*)d_in[26];
  const float* dec_b  = (const float*)d_in[27];
  const float* c3_w   = (const float*)d_in[28];
  const float* c3_b   = (const float*)d_in[29];
  const float* c1_w   = (const float*)d_in[30];
  const float* c1_b   = (const float*)d_in[31];

  float* W = (float*)d_ws;
  float* H            = W;                                  // 4,194,304 f
  unsigned int* ABT   = (unsigned int*)(W + 4194304);       // 2,097,152 u32
  unsigned short* UO  = (unsigned short*)(W + 8388608);     // 4,194,304 sh (P1b/Ub)
  float* R1           = W + 10485760;                       // 8,388,608 f (imat/H0b/ZAb/Y1)
  unsigned short* SbA = (unsigned short*)(W + 18874368);    // 3,145,728 sh
  float* SBa          = W + 20447232;                       // 24,576 f
  unsigned short* taggT = (unsigned short*)(W + 20471808);  // 1,048,576 sh
  unsigned short* mwT1  = (unsigned short*)(W + 20996096);  // 3,145,728 sh
  unsigned short* mwT2  = (unsigned short*)(W + 22568960);  // 3,145,728 sh
  unsigned short* decC  = (unsigned short*)(W + 24141824);  // 1,048,576 sh
  unsigned short* w3t   = (unsigned short*)(W + 24666112);  // 16,384 sh
  unsigned short* btp   = (unsigned short*)(W + 24674304);  // 28,672 sh
  unsigned short* bte   = (unsigned short*)(W + 24688640);  // 32,768 sh
  float* TEMB  = W + 24705024;                              // 2,048
  float* PBP   = W + 24707072;                              // 64
  float* PA    = W + 24707136;                              // 1,024
  float* PB    = W + 24708160;                              // 4,096
  float* PARTC = W + 24712256;                              // 32,768
  float* C1    = W + 24745024;                              // 4,096
  float* C2    = W + 24749120;                              // 4,096

  unsigned short* imat = (unsigned short*)R1;
  unsigned short* H0b  = (unsigned short*)R1;
  unsigned short* Y1   = (unsigned short*)R1;
  unsigned short* ZAb  = (unsigned short*)R1;
  unsigned short* P1b = UO;
  unsigned short* Ub  = UO;
  float* out = (float*)d_out;

  // ---- weight prep (once)
  k_cvt_trans<<<dim3(16,64,1),256,0,stream>>>(tagg_w, taggT, 2048, 512, 0, 0);
  k_cvt_trans<<<dim3(16,16,12),256,0,stream>>>(mw1, mwT1, 512, 512, 262144, 262144);
  k_cvt_trans<<<dim3(16,16,12),256,0,stream>>>(mw2, mwT2, 512, 512, 262144, 262144);
  k_cvt<<<4096,256,0,stream>>>(dec_w, decC, 1048576);
  k_prep_w3<<<36,256,0,stream>>>(c3_w, w3t);
  k_prep_btp<<<112,256,0,stream>>>(patch_w, patch_b, btp, PBP);
  k_prep_bte<<<128,256,0,stream>>>(p1_w, bte);
  k_temb<<<8,256,0,stream>>>(gamma, TEMB);
  k_mode_prep_all<<<12288,256,0,stream>>>(aw1, aw2, ab1, ab2, SbA, SBa);

  // ---- encoder
  k_pack<<<8192,256,0,stream>>>(x, imat);
  k_mgemm<1,1,1><<<dim3(1,512),256,0,stream>>>(imat, btp, PBP, P1b,
      nullptr, nullptr, 448, 448, 64, 0, 0, 0, 0);
  k_mgemm<1,0,2><<<dim3(8,512),256,0,stream>>>(P1b, bte, p1_b, H0b,
      pos, TEMB, 64, 64, 512, 0, 0, 0, 0);
  k_bgemm<0,0><<<256,1024,0,stream>>>(H0b, taggT, H, nullptr, nullptr, nullptr,
      nullptr, PA, 2048, 512, 4);

  for (int d = 0; d < 12; ++d) {
    k_dft_a<<<512,256,0,stream>>>(H, PA, gn1_s + d*512, gn1_b + d*512, ABT);
    k_modes<<<512,256,0,stream>>>(ABT, SbA + (size_t)d*262144, SBa + d*2048);
    k_idft_e<<<512,256,0,stream>>>(ABT, H, PA, gn1_s + d*512, gn1_b + d*512, ZAb, PB);
    k_bgemm<4,1><<<256,1024,0,stream>>>(ZAb, mwT1 + (size_t)d*262144, nullptr, Ub,
        mb1 + d*512, gn2_s + d*512, PB, const_cast<float*>(gn2_b) + d*512, 512, 512, 4);
    if (d < 11)
      k_bgemm<0,2><<<256,1024,0,stream>>>(Ub, mwT2 + (size_t)d*262144, H, nullptr,
          mb2 + d*512, H, nullptr, PA, 512, 512, 4);
    else
      k_bgemm<0,4><<<256,1024,0,stream>>>(Ub, mwT2 + (size_t)d*262144, H, nullptr,
          mb2 + d*512, H, nullptr, PARTC, 512, 512, 4);
  }

  k_cls_l<1><<<dim3(8,8),256,0,stream>>>(PARTC, cls_w1, cls_b1, C1);
  k_cls_l<0><<<dim3(8,8),256,0,stream>>>(C1, cls_w2, cls_b2, C2);
  k_cls3<<<8,768,0,stream>>>(C2, cls_w3, cls_b3, out);
  k_bgemm<1,3><<<1024,1024,0,stream>>>(H, decC, nullptr, Y1,
      dec_b, nullptr, nullptr, nullptr, 512, 0, 16);
  k_tail<<<2048,256,0,stream>>>(Y1, w3t, c1_w, c1_b, out);
}

// Round 14
// 953.452 us; speedup vs baseline: 1.0482x; 1.0482x over previous
//
#include <hip/hip_runtime.h>
#include <cstddef>

typedef __attribute__((ext_vector_type(8))) short bh8;
typedef __attribute__((ext_vector_type(4))) float f4;

__device__ __forceinline__ float gelu_f(float x){
  return 0.5f * x * (1.0f + erff(x * 0.7071067811865476f));
}

__device__ __forceinline__ unsigned short f2bf(float f){
  unsigned int u = __float_as_uint(f);
  unsigned int r = (u + 0x7FFFu + ((u >> 16) & 1u)) >> 16;
  return (unsigned short)r;
}

__device__ __forceinline__ float bf2f(unsigned short u){
  return __uint_as_float(((unsigned int)u) << 16);
}

__device__ __forceinline__ f4 mfma16(bh8 a, bh8 b, f4 c){
  return __builtin_amdgcn_mfma_f32_16x16x32_bf16(a, b, c, 0, 0, 0);
}

__device__ __forceinline__ void gll16(const unsigned short* src, unsigned short* dst){
  __builtin_amdgcn_global_load_lds(
      (const __attribute__((address_space(1))) unsigned int*)src,
      (__attribute__((address_space(3))) unsigned int*)dst, 16, 0, 0);
}

// gn coef from 8-slice partials PA[(b*8+g)*8+q], s2 at +512
__device__ __forceinline__ void gn_coef8(const float* pa, const float* sc,
                                         const float* bi, int b, int c,
                                         float& sca, float& sh)
{
  const int g = c >> 6;
  float s1 = 0.f, s2 = 0.f;
  #pragma unroll
  for (int q = 0; q < 8; ++q) {
    s1 += pa[(b * 8 + g) * 8 + q];
    s2 += pa[512 + (b * 8 + g) * 8 + q];
  }
  const float mu = s1 * (1.0f / 65536.0f);
  const float var = s2 * (1.0f / 65536.0f) - mu * mu;
  const float rs = rsqrtf(var + 1e-5f);
  sca = sc[c] * rs;
  sh = bi[c] - mu * sca;
}

// ================= big bf16 MFMA GEMM
#define BG_STAGE(dbuf, kofs, BASE, DST) \
  gll16(BASE + (size_t)sr_ * K + (kofs) + ((ss_ ^ (sr_ & 7)) << 3), &DST[dbuf][tid * 8]);

#define BG_LOADA(kofs) { \
  if (AMODE == 3 || AMODE == 4) { \
    const unsigned short* ap16 = Ab16 + (size_t)sr_ * K + (kofs) + ss_ * 8; \
    const uint4 uv = *(const uint4*)ap16; \
    ra0.x = bf2f((unsigned short)(uv.x & 0xffffu)); ra0.y = bf2f((unsigned short)(uv.x >> 16)); \
    ra0.z = bf2f((unsigned short)(uv.y & 0xffffu)); ra0.w = bf2f((unsigned short)(uv.y >> 16)); \
    ra1.x = bf2f((unsigned short)(uv.z & 0xffffu)); ra1.y = bf2f((unsigned short)(uv.z >> 16)); \
    ra1.z = bf2f((unsigned short)(uv.w & 0xffffu)); ra1.w = bf2f((unsigned short)(uv.w >> 16)); \
  } else { \
    const float* ap_ = Afbase + (size_t)sr_ * K + (kofs) + ss_ * 8; \
    ra0 = *(const float4*)ap_; \
    ra1 = *(const float4*)(ap_ + 4); \
  } \
  if (AMODE == 2 || AMODE == 3) { \
    const int bb_ = (m0 + sr_) >> 10; \
    const int ch_ = (kofs) + ss_ * 8; \
    const float4 c0_ = *(const float4*)(gnc + bb_ * 512 + ch_); \
    const float4 c1_ = *(const float4*)(gnc + bb_ * 512 + ch_ + 4); \
    const float4 h0_ = *(const float4*)(gnc + 4096 + bb_ * 512 + ch_); \
    const float4 h1_ = *(const float4*)(gnc + 4096 + bb_ * 512 + ch_ + 4); \
    ra0.x = fmaf(ra0.x, c0_.x, h0_.x); ra0.y = fmaf(ra0.y, c0_.y, h0_.y); \
    ra0.z = fmaf(ra0.z, c0_.z, h0_.z); ra0.w = fmaf(ra0.w, c0_.w, h0_.w); \
    ra1.x = fmaf(ra1.x, c1_.x, h1_.x); ra1.y = fmaf(ra1.y, c1_.y, h1_.y); \
    ra1.z = fmaf(ra1.z, c1_.z, h1_.z); ra1.w = fmaf(ra1.w, c1_.w, h1_.w); \
  } \
  if (AMODE == 4) { \
    const int ch_ = (kofs) + ss_ * 8; \
    const float4 c0_ = *(const float4*)(gncs + ch_); \
    const float4 c1_ = *(const float4*)(gncs + ch_ + 4); \
    const float4 h0_ = *(const float4*)(gncs + 512 + ch_); \
    const float4 h1_ = *(const float4*)(gncs + 512 + ch_ + 4); \
    ra0.x = fmaf(ra0.x, c0_.x, h0_.x); ra0.y = fmaf(ra0.y, c0_.y, h0_.y); \
    ra0.z = fmaf(ra0.z, c0_.z, h0_.z); ra0.w = fmaf(ra0.w, c0_.w, h0_.w); \
    ra1.x = fmaf(ra1.x, c1_.x, h1_.x); ra1.y = fmaf(ra1.y, c1_.y, h1_.y); \
    ra1.z = fmaf(ra1.z, c1_.z, h1_.z); ra1.w = fmaf(ra1.w, c1_.w, h1_.w); \
  } }

#define BG_WRITEA(dbuf) { \
  const int slot_ = ss_ ^ (sr_ & 7); \
  bh8 av_; \
  av_[0] = (short)f2bf(ra0.x); av_[1] = (short)f2bf(ra0.y); \
  av_[2] = (short)f2bf(ra0.z); av_[3] = (short)f2bf(ra0.w); \
  av_[4] = (short)f2bf(ra1.x); av_[5] = (short)f2bf(ra1.y); \
  av_[6] = (short)f2bf(ra1.z); av_[7] = (short)f2bf(ra1.w); \
  *(bh8*)(&As[dbuf][sr_ * 64 + slot_ * 8]) = av_; }

template<int AMODE, int OMODE>
__global__ __launch_bounds__(1024)
void k_bgemm(const void* __restrict__ Av, const unsigned short* __restrict__ Bt,
             float* __restrict__ C, unsigned short* __restrict__ OB,
             const float* __restrict__ bias, const float* __restrict__ Res,
             const float* __restrict__ gnc, float* __restrict__ gpart,
             int K, int ldc, int nn)
{
  __shared__ __align__(16) unsigned short As[2][8192];
  __shared__ __align__(16) unsigned short Bs[2][8192];
  __shared__ __align__(16) float gncs[1024];
  const int bid = blockIdx.x, nwg = gridDim.x;
  const int wg = (bid & 7) * (nwg >> 3) + (bid >> 3);
  const int mb = wg / nn;
  const int m0 = mb * 128, n0 = (wg - mb * nn) * 128;
  const int tid = threadIdx.x;
  const int w = tid >> 6, lane = tid & 63;
  const int lr = lane & 15, lh = lane >> 4;
  const int wr = w >> 2, wc = w & 3;
  const int sr_ = tid >> 3, ss_ = tid & 7;
  const unsigned short* Abase = (const unsigned short*)Av + (size_t)m0 * K;
  const unsigned short* Ab16 = (const unsigned short*)Av + (size_t)m0 * K;
  const float* Afbase = (const float*)Av + (size_t)m0 * K;
  const unsigned short* Bbase = Bt + (size_t)n0 * K;
  float4 ra0, ra1;
  f4 acc[2][2] = {};

  if (AMODE == 4) {
    if (tid < 512) {
      const int bq = m0 >> 10, g = tid >> 6;
      float s1 = 0.f, s2 = 0.f;
      #pragma unroll
      for (int q = 0; q < 64; ++q) {
        s1 += gnc[(bq * 8 + g) * 64 + q];
        s2 += gnc[4096 + (bq * 8 + g) * 64 + q];
      }
      const float mu = s1 * (1.0f / 65536.0f);
      const float var = s2 * (1.0f / 65536.0f) - mu * mu;
      const float rs = rsqrtf(var + 1e-5f);
      const float sca = Res[tid] * rs;
      gncs[tid] = sca;
      gncs[512 + tid] = gpart[tid] - mu * sca;
    }
    __syncthreads();
  }

  const int nt = K >> 6;
  if (AMODE == 0) { BG_STAGE(0, 0, Abase, As) }
  else            { BG_LOADA(0) BG_WRITEA(0) }
  BG_STAGE(0, 0, Bbase, Bs)
  __syncthreads();

  for (int t = 0; t < nt; ++t) {
    const int d = t & 1;
    const bool more = (t + 1 < nt);
    if (more) {
      const int kn = (t + 1) << 6;
      if (AMODE == 0) { BG_STAGE(d ^ 1, kn, Abase, As) }
      else            { BG_LOADA(kn) }
      BG_STAGE(d ^ 1, kn, Bbase, Bs)
    }
    #pragma unroll
    for (int kk = 0; kk < 2; ++kk) {
      bh8 af[2], bf[2];
      #pragma unroll
      for (int mi = 0; mi < 2; ++mi) {
        const int R = wr * 32 + mi * 16 + lr;
        af[mi] = *(const bh8*)((const char*)As[d] + R * 128 + (((kk * 4 + lh) ^ (R & 7)) * 16));
      }
      #pragma unroll
      for (int ni = 0; ni < 2; ++ni) {
        const int R = wc * 32 + ni * 16 + lr;
        bf[ni] = *(const bh8*)((const char*)Bs[d] + R * 128 + (((kk * 4 + lh) ^ (R & 7)) * 16));
      }
      #pragma unroll
      for (int mi = 0; mi < 2; ++mi)
        #pragma unroll
        for (int ni = 0; ni < 2; ++ni)
          acc[mi][ni] = mfma16(af[mi], bf[ni], acc[mi][ni]);
    }
    if (more && AMODE != 0) { BG_WRITEA(d ^ 1) }
    __syncthreads();
  }

  float cs1[2], cs2[2];
  #pragma unroll
  for (int ni = 0; ni < 2; ++ni) {
    const int col_l = wc * 32 + ni * 16 + lr;
    const int col = n0 + col_l;
    float bv = 0.f;
    if (OMODE == 1 || OMODE == 2 || OMODE == 4) bv = bias[col];
    if (OMODE == 3) bv = bias[col & 31];
    float s1 = 0.f, s2 = 0.f;
    #pragma unroll
    for (int mi = 0; mi < 2; ++mi) {
      #pragma unroll
      for (int r = 0; r < 4; ++r) {
        const int row = m0 + wr * 32 + mi * 16 + lh * 4 + r;
        float v = acc[mi][ni][r] + bv;
        if (OMODE == 0) {
          C[(size_t)row * ldc + col] = v;
          s1 += v; s2 += v * v;
        } else if (OMODE == 1) {
          OB[(size_t)row * ldc + col] = f2bf(gelu_f(v));
        } else if (OMODE == 2 || OMODE == 4) {
          const size_t ci = (size_t)row * ldc + col;
          v += Res[ci];
          C[ci] = v;
          s1 += v; s2 += v * v;
        } else {
          v = gelu_f(v);
          const int bb = row >> 10, hw = row & 1023, ii = hw >> 5, jj = hw & 31;
          const int dxy = col >> 5, dy = dxy >> 3, dx = dxy & 7, cc = col & 31;
          OB[(((size_t)(bb * 256 + ii * 8 + dy)) * 256 + jj * 8 + dx) * 32 + cc] = f2bf(v);
        }
      }
    }
    cs1[ni] = s1; cs2[ni] = s2;
  }
  if (OMODE == 0 || OMODE == 2 || OMODE == 4) {
    float* sp = (float*)As;
    const int sub = wr * 4 + lh;
    #pragma unroll
    for (int ni = 0; ni < 2; ++ni) {
      const int col_l = wc * 32 + ni * 16 + lr;
      sp[col_l * 16 + sub] = cs1[ni];
      sp[2048 + col_l * 16 + sub] = cs2[ni];
    }
    __syncthreads();
    if (tid < 128) {
      float s1 = 0.f, s2 = 0.f;
      #pragma unroll
      for (int u = 0; u < 16; ++u) { s1 += sp[tid * 16 + u]; s2 += sp[2048 + tid * 16 + u]; }
      const int b = m0 >> 10, slice = (m0 >> 7) & 7;
      if (OMODE == 4) {
        gpart[(b * 8 + slice) * 512 + n0 + tid] = s1;
      } else {
        #pragma unroll
        for (int sft = 32; sft > 0; sft >>= 1) {
          s1 += __shfl_xor(s1, sft, 64);
          s2 += __shfl_xor(s2, sft, 64);
        }
        if ((tid & 63) == 0) {
          const int g = (n0 >> 6) + (tid >> 6);
          gpart[(b * 8 + g) * 8 + slice] = s1;
          gpart[512 + (b * 8 + g) * 8 + slice] = s2;
        }
      }
    }
  }
}

// ================= fused mode pipeline: dft_b + AFNO MLP + idft_d (radix-2 DFTs)
__global__ __launch_bounds__(256)
void k_modes(unsigned int* __restrict__ AB, const unsigned short* __restrict__ Sb_d,
             const float* __restrict__ SB_d)
{
  __shared__ __align__(16) unsigned int ABs[4096];
  __shared__ __align__(16) unsigned short Ws[16384];
  __shared__ __align__(16) unsigned short Ps[4096];
  __shared__ __align__(16) unsigned short O1s[4096];
  __shared__ float ct[512], st[512];
  unsigned short* M2 = (unsigned short*)ABs;

  const int bx = blockIdx.x;
  const int cq = bx & 3, kh = (bx >> 2) & 15, b = bx >> 6;
  const int tid = threadIdx.x;
  const int w = tid >> 6, lane = tid & 63, lr = lane & 15, lh = lane >> 4;
  unsigned int* ABbase = AB + (((size_t)b * 16 + kh) * 32) * 512 + cq * 128;

  #pragma unroll
  for (int p = 0; p < 4; ++p) {
    const int q = p * 256 + tid;
    const int x = q >> 5, c4 = (q & 31) * 4;
    gll16((const unsigned short*)(ABbase + (size_t)x * 512 + c4),
          (unsigned short*)&ABs[q * 4]);
  }
  {
    const unsigned short* Wsrc = Sb_d + (size_t)(cq * 2) * 16384;
    #pragma unroll
    for (int p = 0; p < 8; ++p) {
      const int q = p * 256 + tid;
      const int r = q >> 4, c = q & 15;
      gll16(Wsrc + r * 128 + ((c ^ (r & 7)) << 3), &Ws[q * 8]);
    }
  }
  for (int q = tid; q < 512; q += 256) {
    const int k = q >> 5, xx = q & 31;
    const float ang = (float)((k * xx) & 31) * 0.19634954084936207f;
    ct[q] = cosf(ang); st[q] = sinf(ang);
  }
  __syncthreads();

  // ---- dft_b (radix-2)
  const int cc = tid & 127, kp2 = tid >> 7;
  {
    float gr[8], gi[8];
    #pragma unroll
    for (int j = 0; j < 8; ++j) { gr[j] = 0.f; gi[j] = 0.f; }
    for (int x = 0; x < 16; ++x) {
      const unsigned int p1 = ABs[x * 128 + cc];
      const unsigned int p2 = ABs[(x + 16) * 128 + cc];
      const float vr1 = bf2f((unsigned short)(p1 & 0xffffu));
      const float vi1 = bf2f((unsigned short)(p1 >> 16));
      const float vr2 = bf2f((unsigned short)(p2 & 0xffffu));
      const float vi2 = bf2f((unsigned short)(p2 >> 16));
      const float vr = kp2 ? (vr1 - vr2) : (vr1 + vr2);
      const float vi = kp2 ? (vi1 - vi2) : (vi1 + vi2);
      #pragma unroll
      for (int j = 0; j < 8; ++j) {
        const int kg = 2 * j + kp2;
        const float c_ = ct[kg * 32 + x], s_ = st[kg * 32 + x];
        gr[j] += vr * c_ + vi * s_;
        gi[j] += vi * c_ - vr * s_;
      }
    }
    const int cblk = cc >> 6, ci = cc & 63;
    #pragma unroll
    for (int j = 0; j < 8; ++j) {
      const int kw = 2 * j + kp2;
      const int base = cblk * 2048 + kw * 128;
      const int chr = (ci >> 3) ^ (kw & 7);
      const int chi = ((64 + ci) >> 3) ^ (kw & 7);
      Ps[base + (chr << 3) + (ci & 7)] = f2bf(gr[j] * (1.0f / 32.0f));
      Ps[base + (chi << 3) + (ci & 7)] = f2bf(gi[j] * (1.0f / 32.0f));
    }
  }
  __syncthreads();

  // ---- AFNO: 4 iters, W single-buffer
  for (int i = 0; i < 4; ++i) {
    const int cblk = i & 1;
    const unsigned short* src = (i < 2) ? Ps : O1s;
    f4 acc[2] = {};
    #pragma unroll
    for (int ks = 0; ks < 4; ++ks) {
      const bh8 a = *(const bh8*)(&src[cblk * 2048 + lr * 128
                      + (((ks * 4 + lh) ^ (lr & 7)) << 3)]);
      #pragma unroll
      for (int j = 0; j < 2; ++j) {
        const int rw = (w * 2 + j) * 16 + lr;
        const bh8 bb = *(const bh8*)(&Ws[rw * 128 + (((ks * 4 + lh) ^ (rw & 7)) << 3)]);
        acc[j] = mfma16(a, bb, acc[j]);
      }
    }
    const int z = cq * 2 + cblk;
    #pragma unroll
    for (int j = 0; j < 2; ++j) {
      const int o = (w * 2 + j) * 16 + lr;
      if (i < 2) {
        const float bv = SB_d[z * 128 + o];
        #pragma unroll
        for (int r = 0; r < 4; ++r) {
          const int kw = lh * 4 + r;
          const int ch = (o >> 3) ^ (kw & 7);
          O1s[cblk * 2048 + kw * 128 + (ch << 3) + (o & 7)] = f2bf(gelu_f(acc[j][r] + bv));
        }
      } else {
        const float bv = SB_d[1024 + z * 128 + o];
        #pragma unroll
        for (int r = 0; r < 4; ++r) {
          const int kw = lh * 4 + r;
          M2[cblk * 2048 + kw * 128 + o] = f2bf(acc[j][r] + bv);
        }
      }
    }
    __syncthreads();
    if (i < 3) {
      const int j2 = i + 1;
      const unsigned short* Wsrc = Sb_d + (j2 >= 2 ? 131072 : 0)
                                 + (size_t)(cq * 2 + (j2 & 1)) * 16384;
      #pragma unroll
      for (int p = 0; p < 8; ++p) {
        const int q = p * 256 + tid;
        const int r = q >> 4, c = q & 15;
        gll16(Wsrc + r * 128 + ((c ^ (r & 7)) << 3), &Ws[q * 8]);
      }
      __syncthreads();
    }
  }

  // ---- idft_d (radix-2): pair outputs (x, x+16)
  {
    const int xh = tid >> 7;
    const int cblk = cc >> 6, ci = cc & 63;
    float gr[16], gi[16];
    #pragma unroll
    for (int kw = 0; kw < 16; ++kw) {
      const float wf = (kw == 0) ? 1.0f : 2.0f;
      gr[kw] = wf * bf2f(M2[cblk * 2048 + kw * 128 + ci]);
      gi[kw] = wf * bf2f(M2[cblk * 2048 + kw * 128 + 64 + ci]);
    }
    for (int x = xh * 8; x < xh * 8 + 8; ++x) {
      float Er = 0.f, Ei = 0.f, Or = 0.f, Oi = 0.f;
      #pragma unroll
      for (int j = 0; j < 8; ++j) {
        const int ke = 2 * j, ko = 2 * j + 1;
        const float ce = ct[ke * 32 + x], se = st[ke * 32 + x];
        const float co = ct[ko * 32 + x], so = st[ko * 32 + x];
        Er += gr[ke] * ce - gi[ke] * se;
        Ei += gi[ke] * ce + gr[ke] * se;
        Or += gr[ko] * co - gi[ko] * so;
        Oi += gi[ko] * co + gr[ko] * so;
      }
      ABbase[(size_t)x * 512 + cc] =
          (unsigned int)f2bf(Er + Or) | ((unsigned int)f2bf(Ei + Oi) << 16);
      ABbase[(size_t)(x + 16) * 512 + cc] =
          (unsigned int)f2bf(Er - Or) | ((unsigned int)f2bf(Ei - Oi) << 16);
    }
  }
}

// ---------------- im2col pack: x -> bf16 imat [32768][448]
__global__ __launch_bounds__(256)
void k_pack(const float* __restrict__ x, unsigned short* __restrict__ imat)
{
  const int nb = blockIdx.x;
  const int j = nb & 31, i = (nb >> 5) & 31, b = nb >> 10;
  const int tid = threadIdx.x;
  const int tl = tid >> 6, px = tid & 63;
  const int dy = px >> 3, dx = px & 7;
  const int Y = i * 8 + dy, X = j * 8 + dx;
  const float4 v = *(const float4*)(x + (((size_t)(b * 256 + Y)) * 256 + X) * 16 + tl * 4);
  const size_t row = (size_t)nb * 4 + tl;
  ushort4 ov;
  ov.x = f2bf(v.x); ov.y = f2bf(v.y); ov.z = f2bf(v.z); ov.w = f2bf(v.w);
  *(ushort4*)(imat + row * 448 + px * 4) = ov;
  for (int q = tid; q < 768; q += 256) {
    const int tt = q / 192, r = q - tt * 192;
    const int sec = r >> 6, p2 = r & 63;
    float val;
    if (sec == 0)      val = (float)(i * 8 + (p2 >> 3)) * (1.0f / 255.0f);
    else if (sec == 1) val = (float)(j * 8 + (p2 & 7)) * (1.0f / 255.0f);
    else               val = (float)tt * (1.0f / 3.0f);
    imat[((size_t)nb * 4 + tt) * 448 + 256 + sec * 64 + p2] = f2bf(val);
  }
}

// ---------------- prep Bt_patch [64][448] (+ padded bias)
__global__ __launch_bounds__(256)
void k_prep_btp(const float* __restrict__ pw, const float* __restrict__ pb,
                unsigned short* __restrict__ btp, float* __restrict__ pbp)
{
  const int idx = blockIdx.x * 256 + threadIdx.x;
  if (idx < 28672) {
    const int n = idx / 448, k = idx - (idx / 448) * 448;
    int l;
    if (k < 256) { const int pxx = k >> 2, c = k & 3; l = pxx * 7 + c; }
    else { const int sec = (k - 256) >> 6, p2 = (k - 256) & 63; l = p2 * 7 + 4 + sec; }
    btp[n * 448 + k] = (n < 35) ? f2bf(pw[l * 35 + n]) : (unsigned short)0;
  }
  if (idx < 64) pbp[idx] = (idx < 35) ? pb[idx] : 0.0f;
}

// ---------------- prep Bt_embed [512][64]
__global__ __launch_bounds__(256)
void k_prep_bte(const float* __restrict__ w, unsigned short* __restrict__ bte)
{
  const int idx = blockIdx.x * 256 + threadIdx.x;
  const int n = idx >> 6, k = idx & 63;
  bte[idx] = (k < 35) ? f2bf(w[k * 512 + n]) : (unsigned short)0;
}

// ---------------- temb table [4][512]
__global__ __launch_bounds__(256)
void k_temb(const float* __restrict__ gamma, float* __restrict__ temb)
{
  const int idx = blockIdx.x * 256 + threadIdx.x;
  const int t = idx >> 9, e = idx & 511;
  temb[idx] = cosf((float)t * (1.0f / 3.0f) * gamma[e]);
}

// ---------------- weight prep: fp32 [K][N] -> bf16 [N][K]
__global__ __launch_bounds__(256)
void k_cvt_trans(const float* __restrict__ in, unsigned short* __restrict__ out,
                 int K, int N, long long sIn, long long sOut)
{
  __shared__ float tile[32][33];
  const int z = blockIdx.z;
  in  += (size_t)z * sIn;
  out += (size_t)z * sOut;
  const int n0 = blockIdx.x * 32, k0 = blockIdx.y * 32;
  const int tx = threadIdx.x & 31, ty = threadIdx.x >> 5;
  #pragma unroll
  for (int i = 0; i < 4; ++i)
    tile[ty + i * 8][tx] = in[(size_t)(k0 + ty + i * 8) * N + n0 + tx];
  __syncthreads();
  #pragma unroll
  for (int i = 0; i < 4; ++i)
    out[(size_t)(n0 + ty + i * 8) * K + k0 + tx] = f2bf(tile[tx][ty + i * 8]);
}

__global__ __launch_bounds__(256)
void k_cvt(const float* __restrict__ in, unsigned short* __restrict__ out, int n)
{
  const int idx = blockIdx.x * 256 + threadIdx.x;
  if (idx < n) out[idx] = f2bf(in[idx]);
}

__global__ __launch_bounds__(256)
void k_prep_w3(const float* __restrict__ w, unsigned short* __restrict__ out)
{
  const int idx = blockIdx.x * 256 + threadIdx.x;
  if (idx < 9216) {
    const int kb = idx >> 10, co = (idx >> 5) & 31, ci = idx & 31;
    out[idx] = f2bf(w[(kb * 32 + ci) * 32 + co]);
  }
}

// ---------------- small bf16 MFMA GEMM, 64x64 tile, z-batched (patch/embed)
template<int BIAS, int GELU, int OMODE>
__global__ __launch_bounds__(256)
void k_mgemm(const unsigned short* __restrict__ A, const unsigned short* __restrict__ Bt,
             const float* __restrict__ bias, unsigned short* __restrict__ OB,
             const float* __restrict__ pos, const float* __restrict__ temb,
             int K, int lda, int ldc,
             long long zsA, long long zsB, long long zsC, int zsBias)
{
  __shared__ __align__(16) unsigned short As[64 * 40];
  __shared__ __align__(16) unsigned short Bs[64 * 40];
  const int z = blockIdx.z;
  A  += (size_t)z * zsA;
  Bt += (size_t)z * zsB;
  if (BIAS) bias += (size_t)z * zsBias;
  OB += (size_t)z * zsC;
  const int m0 = blockIdx.y * 64, n0 = blockIdx.x * 64;
  const int tid = threadIdx.x;
  const int w = tid >> 6, l = tid & 63;
  const int lr = l & 15, lh = l >> 4;
  const int sr = tid >> 2, skq = (tid & 3) * 8;
  f4 acc[4] = {};
  for (int k0 = 0; k0 < K; k0 += 32) {
    const uint4 av = *(const uint4*)(A + (size_t)(m0 + sr) * lda + k0 + skq);
    *(uint4*)(&As[sr * 40 + skq]) = av;
    const uint4 bv = *(const uint4*)(Bt + (size_t)(n0 + sr) * K + k0 + skq);
    *(uint4*)(&Bs[sr * 40 + skq]) = bv;
    __syncthreads();
    const bh8 af = *(const bh8*)(&As[(w * 16 + lr) * 40 + lh * 8]);
    #pragma unroll
    for (int ct = 0; ct < 4; ++ct) {
      const bh8 bf = *(const bh8*)(&Bs[(ct * 16 + lr) * 40 + lh * 8]);
      acc[ct] = mfma16(af, bf, acc[ct]);
    }
    __syncthreads();
  }
  #pragma unroll
  for (int ct = 0; ct < 4; ++ct) {
    const int col = n0 + ct * 16 + lr;
    float bv = 0.f;
    if (BIAS) bv = bias[col];
    #pragma unroll
    for (int r = 0; r < 4; ++r) {
      const int row = m0 + w * 16 + lh * 4 + r;
      float v = acc[ct][r] + bv;
      if (GELU) v = gelu_f(v);
      if (OMODE == 2) {
        const int hw = (row >> 2) & 1023, t = row & 3;
        v = (v + pos[(size_t)hw * 512 + col]) * temb[t * 512 + col];
        OB[(size_t)row * 512 + col] = f2bf(v);
      } else {
        OB[(size_t)row * ldc + col] = f2bf(v);
      }
    }
  }
}

// ---------------- decoder tail: conv3x3 (MFMA) + gelu + 1x1 -> out
__global__ __launch_bounds__(256)
void k_tail(const unsigned short* __restrict__ Y1, const unsigned short* __restrict__ w3t,
            const float* __restrict__ c1w, const float* __restrict__ c1b,
            float* __restrict__ outp)
{
  __shared__ __align__(16) char lbuf[256 * 33 * 4];
  __shared__ float c1s[128];
  unsigned short* it = (unsigned short*)lbuf;
  float* y2 = (float*)lbuf;
  const int bx = blockIdx.x;
  const int b = bx >> 8, ty = (bx >> 4) & 15, tx = bx & 15;
  const int Y0 = ty * 16, X0 = tx * 16;
  const int tid = threadIdx.x;
  const int w = tid >> 6, l = tid & 63, lr = l & 15, lh = l >> 4;

  if (tid < 128) c1s[tid] = c1w[tid];
  for (int idx = tid; idx < 1296; idx += 256) {
    const int r = idx / 72, rem = idx - r * 72, c = rem >> 2, q = rem & 3;
    const int Yg = Y0 + r - 1, Xg = X0 + c - 1;
    uint4 v = make_uint4(0u, 0u, 0u, 0u);
    if (Yg >= 0 && Yg < 256 && Xg >= 0 && Xg < 256)
      v = *(const uint4*)(Y1 + (((size_t)(b * 256 + Yg)) * 256 + Xg) * 32 + q * 8);
    *(uint4*)(&it[(r * 18 + c) * 40 + q * 8]) = v;
  }
  bh8 bw[2][9];
  #pragma unroll
  for (int ct = 0; ct < 2; ++ct)
    #pragma unroll
    for (int kb = 0; kb < 9; ++kb)
      bw[ct][kb] = *(const bh8*)(w3t + (size_t)(kb * 32 + ct * 16 + lr) * 32 + lh * 8);
  __syncthreads();

  f4 acc[4][2] = {};
  #pragma unroll
  for (int kb = 0; kb < 9; ++kb) {
    const int dy = kb / 3, dx = kb % 3;
    #pragma unroll
    for (int yy = 0; yy < 4; ++yy) {
      const int y = w * 4 + yy;
      const bh8 af = *(const bh8*)(&it[((y + dy) * 18 + lr + dx) * 40 + lh * 8]);
      acc[yy][0] = mfma16(af, bw[0][kb], acc[yy][0]);
      acc[yy][1] = mfma16(af, bw[1][kb], acc[yy][1]);
    }
  }
  __syncthreads();
  #pragma unroll
  for (int yy = 0; yy < 4; ++yy) {
    const int y = w * 4 + yy;
    #pragma unroll
    for (int ct = 0; ct < 2; ++ct)
      #pragma unroll
      for (int r = 0; r < 4; ++r)
        y2[(y * 16 + lh * 4 + r) * 33 + ct * 16 + lr] = gelu_f(acc[yy][ct][r]);
  }
  __syncthreads();
  const int py = tid >> 4, px = tid & 15;
  float o0 = c1b[0], o1 = c1b[1], o2 = c1b[2], o3 = c1b[3];
  #pragma unroll 8
  for (int ci = 0; ci < 32; ++ci) {
    const float v = y2[tid * 33 + ci];
    o0 = fmaf(v, c1s[ci * 4 + 0], o0);
    o1 = fmaf(v, c1s[ci * 4 + 1], o1);
    o2 = fmaf(v, c1s[ci * 4 + 2], o2);
    o3 = fmaf(v, c1s[ci * 4 + 3], o3);
  }
  float4 ov; ov.x = o0; ov.y = o1; ov.z = o2; ov.w = o3;
  *(float4*)(outp + (((size_t)(b * 256 + Y0 + py)) * 256 + X0 + px) * 4) = ov;
}

// ---------------- forward DFT stage A (radix-2; kp = k parity) -> packed bf16 AB
__global__ __launch_bounds__(256)
void k_dft_a(const float* __restrict__ H, const float* __restrict__ PA,
             const float* __restrict__ sc, const float* __restrict__ bi,
             unsigned int* __restrict__ AB)
{
  __shared__ float ct[512], st[512];
  const int tid = threadIdx.x;
  for (int q = tid; q < 512; q += 256) {
    const int k = q >> 5, y = q & 31;
    const float ang = (float)((k * y) & 31) * 0.19634954084936207f;
    ct[q] = cosf(ang); st[q] = sinf(ang);
  }
  __syncthreads();
  const int blk = blockIdx.x;                    // b*128 + x*4 + half*2 + kp
  const int kp = blk & 1, half = (blk >> 1) & 1, x = (blk >> 2) & 31, b = blk >> 7;
  const int c = half * 256 + tid;
  float sca, sh;
  gn_coef8(PA, sc, bi, b, c, sca, sh);
  float ar[8], ai[8];
  #pragma unroll
  for (int k = 0; k < 8; ++k) { ar[k] = 0.f; ai[k] = 0.f; }
  const float* zp = H + ((size_t)b * 1024 + x) * 512 + c;
  for (int y = 0; y < 16; ++y) {
    const float u  = fmaf(zp[(size_t)y * 16384], sca, sh);
    const float w2 = fmaf(zp[(size_t)(y + 16) * 16384], sca, sh);
    const float v = kp ? (u - w2) : (u + w2);
    #pragma unroll
    for (int k = 0; k < 8; ++k) {
      const int kg = 2 * k + kp;
      ar[k] = fmaf(v, ct[kg * 32 + y], ar[k]);
      ai[k] = fmaf(-v, st[kg * 32 + y], ai[k]);
    }
  }
  #pragma unroll
  for (int k = 0; k < 8; ++k) {
    const int kg = 2 * k + kp;
    const size_t o = (((size_t)b * 16 + kg) * 32 + x) * 512 + c;
    AB[o] = (unsigned int)f2bf(ar[k]) | ((unsigned int)f2bf(ai[k]) << 16);
  }
}

// ---------------- merged AFNO weights for ALL layers
__global__ __launch_bounds__(256)
void k_mode_prep_all(const float* __restrict__ aw1, const float* __restrict__ aw2,
                     const float* __restrict__ ab1, const float* __restrict__ ab2,
                     unsigned short* __restrict__ Sb, float* __restrict__ SB)
{
  const int gi = blockIdx.x * 256 + threadIdx.x;
  const int dd = gi >> 18;
  const int idx = gi & 262143;
  const float* aw1_d = aw1 + (size_t)dd * 65536;
  const float* aw2_d = aw2 + (size_t)dd * 65536;
  const int s = idx >> 17;
  const int blk = (idx >> 14) & 7;
  const int n = (idx >> 7) & 127;
  const int kk = idx & 127;
  const float* aw = s ? aw2_d : aw1_d;
  const int i = kk & 63, o = n & 63;
  const float wr = aw[(blk * 64 + i) * 64 + o];
  const float wi = aw[32768 + (blk * 64 + i) * 64 + o];
  float val;
  if (n < 64) val = (kk < 64) ? wr : -wi;
  else        val = (kk < 64) ? wi :  wr;
  Sb[gi] = f2bf(val);
  if (idx < 2048) {
    const int s2 = idx >> 10, r2 = idx & 1023, b2 = r2 >> 7, q2 = r2 & 127;
    const float* ab = s2 ? (ab2 + dd * 1024) : (ab1 + dd * 1024);
    SB[dd * 2048 + idx] = (q2 < 64) ? ab[b2 * 64 + q2] : ab[512 + b2 * 64 + (q2 - 64)];
  }
}

// ---------------- inverse DFT stage E (radix-2 y-pairs) + residual + gn2 partials
__global__ __launch_bounds__(256)
void k_idft_e(const unsigned int* __restrict__ Tp, const float* __restrict__ H,
              const float* __restrict__ PA, const float* __restrict__ sc,
              const float* __restrict__ bi, unsigned short* __restrict__ zab,
              float* __restrict__ PB)
{
  __shared__ float ct[512], st[512];
  const int tid = threadIdx.x;
  for (int q = tid; q < 512; q += 256) {
    const int k = q >> 5, y = q & 31;
    const float ang = (float)((k * y) & 31) * 0.19634954084936207f;
    ct[q] = cosf(ang); st[q] = sinf(ang);
  }
  __syncthreads();
  const int blk = blockIdx.x;                 // b*128 + x*4 + half*2 + yh
  const int yh = blk & 1, half = (blk >> 1) & 1, x = (blk >> 2) & 31, b = blk >> 7;
  const int c = half * 256 + tid;
  float sca, sh;
  gn_coef8(PA, sc, bi, b, c, sca, sh);
  float trv[16], tiv[16];
  #pragma unroll
  for (int k = 0; k < 16; ++k) {
    const size_t o = (((size_t)b * 16 + k) * 32 + x) * 512 + c;
    const unsigned int pv = Tp[o];
    trv[k] = bf2f((unsigned short)(pv & 0xffffu));
    tiv[k] = bf2f((unsigned short)(pv >> 16));
  }
  float s1 = 0.f, s2 = 0.f;
  for (int y = yh * 8; y < yh * 8 + 8; ++y) {
    float Ev = 0.f, Ov = 0.f;
    #pragma unroll
    for (int j = 0; j < 8; ++j) {
      const int ke = 2 * j, ko = 2 * j + 1;
      Ev += trv[ke] * ct[ke * 32 + y] - tiv[ke] * st[ke * 32 + y];
      Ov += trv[ko] * ct[ko * 32 + y] - tiv[ko] * st[ko * 32 + y];
    }
    const size_t o1 = ((size_t)b * 1024 + y * 32 + x) * 512 + c;
    const size_t o2 = ((size_t)b * 1024 + (y + 16) * 32 + x) * 512 + c;
    const float zv1 = (Ev + Ov) * (1.0f / 32.0f) + fmaf(H[o1], sca, sh);
    const float zv2 = (Ev - Ov) * (1.0f / 32.0f) + fmaf(H[o2], sca, sh);
    zab[o1] = f2bf(zv1);
    zab[o2] = f2bf(zv2);
    s1 += zv1 + zv2; s2 += zv1 * zv1 + zv2 * zv2;
  }
  #pragma unroll
  for (int sft = 32; sft > 0; sft >>= 1) {
    s1 += __shfl_xor(s1, sft, 64);
    s2 += __shfl_xor(s2, sft, 64);
  }
  if ((tid & 63) == 0) {
    const int g = half * 4 + (tid >> 6);
    PB[(b * 8 + g) * 64 + x * 2 + yh] = s1;
    PB[4096 + (b * 8 + g) * 64 + x * 2 + yh] = s2;
  }
}

// ---------------- cls layers 1/2 (ILP-4 accumulators)
template<int FIRST>
__global__ __launch_bounds__(256)
void k_cls_l(const float* __restrict__ src, const float* __restrict__ Wm,
             const float* __restrict__ bb, float* __restrict__ Cout)
{
  __shared__ float tok[512];
  __shared__ float red[256];
  const int b = blockIdx.y, oc = blockIdx.x;
  const int tid = threadIdx.x;
  for (int i = tid; i < 512; i += 256) {
    if (FIRST) {
      float s = 0.f;
      #pragma unroll
      for (int q = 0; q < 8; ++q) s += src[((b * 8 + q) << 9) + i];
      tok[i] = s * (1.0f / 1024.0f);
    } else {
      tok[i] = src[b * 512 + i];
    }
  }
  __syncthreads();
  const int to = tid & 63, iq = tid >> 6;
  const int o = oc * 64 + to;
  const float* wp = Wm + (size_t)(iq * 128) * 512 + o;
  const float* tp = tok + iq * 128;
  float a0 = 0.f, a1 = 0.f, a2 = 0.f, a3 = 0.f;
  #pragma unroll 8
  for (int i = 0; i < 128; i += 4) {
    a0 = fmaf(tp[i + 0], wp[(size_t)(i + 0) * 512], a0);
    a1 = fmaf(tp[i + 1], wp[(size_t)(i + 1) * 512], a1);
    a2 = fmaf(tp[i + 2], wp[(size_t)(i + 2) * 512], a2);
    a3 = fmaf(tp[i + 3], wp[(size_t)(i + 3) * 512], a3);
  }
  red[tid] = (a0 + a1) + (a2 + a3);
  __syncthreads();
  if (tid < 64) {
    const int oo = oc * 64 + tid;
    const float v = red[tid] + red[tid + 64] + red[tid + 128] + red[tid + 192] + bb[oo];
    Cout[b * 512 + oo] = gelu_f(v);
  }
}

// ---------------- cls layer 3
__global__ __launch_bounds__(768)
void k_cls3(const float* __restrict__ C2, const float* __restrict__ w3,
            const float* __restrict__ b3, float* __restrict__ outp)
{
  const int b = blockIdx.x, tid = threadIdx.x;
  const int o = tid >> 6, lane = tid & 63;
  float acc = 0.f;
  for (int i = lane; i < 512; i += 64)
    acc = fmaf(C2[b * 512 + i], w3[i * 12 + o], acc);
  #pragma unroll
  for (int s = 32; s > 0; s >>= 1) acc += __shfl_xor(acc, s, 64);
  if (lane == 0) outp[2097152 + b * 12 + o] = acc + b3[o];
}

extern "C" void kernel_launch(void* const* d_in, const int* in_sizes, int n_in,
                              void* d_out, int out_size, void* d_ws, size_t ws_size,
                              hipStream_t stream)
{
  (void)in_sizes; (void)n_in; (void)out_size; (void)ws_size;
  const float* x      = (const float*)d_in[0];
  const float* patch_w= (const float*)d_in[1];
  const float* patch_b= (const float*)d_in[2];
  const float* p1_w   = (const float*)d_in[3];
  const float* p1_b   = (const float*)d_in[4];
  const float* pos    = (const float*)d_in[5];
  const float* tagg_w = (const float*)d_in[6];
  const float* gamma  = (const float*)d_in[7];
  const float* gn1_s  = (const float*)d_in[8];
  const float* gn1_b  = (const float*)d_in[9];
  const float* aw1    = (const float*)d_in[10];
  const float* ab1    = (const float*)d_in[11];
  const float* aw2    = (const float*)d_in[12];
  const float* ab2    = (const float*)d_in[13];
  const float* gn2_s  = (const float*)d_in[14];
  const float* gn2_b  = (const float*)d_in[15];
  const float* mw1    = (const float*)d_in[16];
  const float* mb1    = (const float*)d_in[17];
  const float* mw2    = (const float*)d_in[18];
  const float* mb2    = (const float*)d_in[19];
  const float* cls_w1 = (const float*)d_in[20];
  const float* cls_b1 = (const float*)d_in[21];
  const float* cls_w2 = (const float*)d_in[22];
  const float* cls_b2 = (const float*)d_in[23];
  const float* cls_w3 = (const float*)d_in[24];
  const float* cls_b3 = (const float*)d_in[25];
  const float* dec_w  = (const float*)d_in[26];
  const float* dec_b  = (const float*)d_in[27];
  const float* c3_w   = (const float*)d_in[28];
  const float* c3_b   = (const float*)d_in[29];
  const float* c1_w   = (const float*)d_in[30];
  const float* c1_b   = (const float*)d_in[31];

  float* W = (float*)d_ws;
  float* H            = W;                                  // 4,194,304 f
  unsigned int* ABT   = (unsigned int*)(W + 4194304);       // 2,097,152 u32
  unsigned short* UO  = (unsigned short*)(W + 8388608);     // 4,194,304 sh (P1b/Ub)
  float* R1           = W + 10485760;                       // 8,388,608 f (imat/H0b/ZAb/Y1)
  unsigned short* SbA = (unsigned short*)(W + 18874368);    // 3,145,728 sh
  float* SBa          = W + 20447232;                       // 24,576 f
  unsigned short* taggT = (unsigned short*)(W + 20471808);  // 1,048,576 sh
  unsigned short* mwT1  = (unsigned short*)(W + 20996096);  // 3,145,728 sh
  unsigned short* mwT2  = (unsigned short*)(W + 22568960);  // 3,145,728 sh
  unsigned short* decC  = (unsigned short*)(W + 24141824);  // 1,048,576 sh
  unsigned short* w3t   = (unsigned short*)(W + 24666112);  // 16,384 sh
  unsigned short* btp   = (unsigned short*)(W + 24674304);  // 28,672 sh
  unsigned short* bte   = (unsigned short*)(W + 24688640);  // 32,768 sh
  float* TEMB  = W + 24705024;                              // 2,048
  float* PBP   = W + 24707072;                              // 64
  float* PA    = W + 24707136;                              // 1,024
  float* PB    = W + 24708160;                              // 8,192
  float* PARTC = W + 24716352;                              // 32,768
  float* C1    = W + 24749120;                              // 4,096
  float* C2    = W + 24753216;                              // 4,096

  unsigned short* imat = (unsigned short*)R1;
  unsigned short* H0b  = (unsigned short*)R1;
  unsigned short* Y1   = (unsigned short*)R1;
  unsigned short* ZAb  = (unsigned short*)R1;
  unsigned short* P1b = UO;
  unsigned short* Ub  = UO;
  float* out = (float*)d_out;

  // ---- weight prep (once)
  k_cvt_trans<<<dim3(16,64,1),256,0,stream>>>(tagg_w, taggT, 2048, 512, 0, 0);
  k_cvt_trans<<<dim3(16,16,12),256,0,stream>>>(mw1, mwT1, 512, 512, 262144, 262144);
  k_cvt_trans<<<dim3(16,16,12),256,0,stream>>>(mw2, mwT2, 512, 512, 262144, 262144);
  k_cvt<<<4096,256,0,stream>>>(dec_w, decC, 1048576);
  k_prep_w3<<<36,256,0,stream>>>(c3_w, w3t);
  k_prep_btp<<<112,256,0,stream>>>(patch_w, patch_b, btp, PBP);
  k_prep_bte<<<128,256,0,stream>>>(p1_w, bte);
  k_temb<<<8,256,0,stream>>>(gamma, TEMB);
  k_mode_prep_all<<<12288,256,0,stream>>>(aw1, aw2, ab1, ab2, SbA, SBa);

  // ---- encoder
  k_pack<<<8192,256,0,stream>>>(x, imat);
  k_mgemm<1,1,1><<<dim3(1,512),256,0,stream>>>(imat, btp, PBP, P1b,
      nullptr, nullptr, 448, 448, 64, 0, 0, 0, 0);
  k_mgemm<1,0,2><<<dim3(8,512),256,0,stream>>>(P1b, bte, p1_b, H0b,
      pos, TEMB, 64, 64, 512, 0, 0, 0, 0);
  k_bgemm<0,0><<<256,1024,0,stream>>>(H0b, taggT, H, nullptr, nullptr, nullptr,
      nullptr, PA, 2048, 512, 4);

  for (int d = 0; d < 12; ++d) {
    k_dft_a<<<1024,256,0,stream>>>(H, PA, gn1_s + d*512, gn1_b + d*512, ABT);
    k_modes<<<512,256,0,stream>>>(ABT, SbA + (size_t)d*262144, SBa + d*2048);
    k_idft_e<<<1024,256,0,stream>>>(ABT, H, PA, gn1_s + d*512, gn1_b + d*512, ZAb, PB);
    k_bgemm<4,1><<<256,1024,0,stream>>>(ZAb, mwT1 + (size_t)d*262144, nullptr, Ub,
        mb1 + d*512, gn2_s + d*512, PB, const_cast<float*>(gn2_b) + d*512, 512, 512, 4);
    if (d < 11)
      k_bgemm<0,2><<<256,1024,0,stream>>>(Ub, mwT2 + (size_t)d*262144, H, nullptr,
          mb2 + d*512, H, nullptr, PA, 512, 512, 4);
    else
      k_bgemm<0,4><<<256,1024,0,stream>>>(Ub, mwT2 + (size_t)d*262144, H, nullptr,
          mb2 + d*512, H, nullptr, PARTC, 512, 512, 4);
  }

  k_cls_l<1><<<dim3(8,8),256,0,stream>>>(PARTC, cls_w1, cls_b1, C1);
  k_cls_l<0><<<dim3(8,8),256,0,stream>>>(C1, cls_w2, cls_b2, C2);
  k_cls3<<<8,768,0,stream>>>(C2, cls_w3, cls_b3, out);
  k_bgemm<1,3><<<1024,1024,0,stream>>>(H, decC, nullptr, Y1,
      dec_b, nullptr, nullptr, nullptr, 512, 0, 16);
  k_tail<<<2048,256,0,stream>>>(Y1, w3t, c1_w, c1_b, out);
}